// Round 8
// baseline (428.688 us; speedup 1.0000x reference)
//
#include <hip/hip_runtime.h>
#include <hip/hip_bf16.h>

// Problem constants
#define N_ATOM 2000
#define MNBR   12
#define OFEA   92
#define AF     64
#define BFEA   41
#define K1     169   // 2A+B
#define O1     128
#define OE     82
#define K3     274   // 3A+2B
#define NM     24000
#define NCONV  3
#define HID    128
#define NCRY   64
#define EPS_BN 1e-5f

#define LDA_T  192   // bf16 TOT leading dim (169 padded to 192)
#define LDH    512   // REST (bf16): [h(0..127)|he(128..209)|pad|P'(256..383)|Q'(384..511)]
#define LDSW   88    // LDS row pitch (ushorts) for MFMA tiles

typedef __bf16 bf16x8 __attribute__((ext_vector_type(8)));
typedef float  f32x4  __attribute__((ext_vector_type(4)));

// v_rcp_f32 (~1 ulp) instead of IEEE division sequence (~9 instrs)
__device__ __forceinline__ float sigmoidf_(float x){
    return __builtin_amdgcn_rcpf(1.f + __expf(-x));
}
__device__ __forceinline__ float softplusf_(float x){
    return fmaxf(x,0.f) + __logf(1.f + __expf(-fabsf(x)));
}
__device__ __forceinline__ float b2f(__hip_bfloat16 v){ return __bfloat162float(v); }

// ================= bf16 MFMA GEMM: REST[r,c] = bf16(bias[c] + sum_k A[r,k]*W[c,k])
__global__ __launch_bounds__(256)
void gemm_bf16(const __hip_bfloat16* __restrict__ A,
               const __hip_bfloat16* __restrict__ W,
               const float* __restrict__ bias,
               __hip_bfloat16* __restrict__ C)
{
    __shared__ unsigned short As[128][LDSW];
    __shared__ unsigned short Ws[128][LDSW];
    const int tid  = threadIdx.x;
    const int row0 = blockIdx.x * 128;
    const int col0 = blockIdx.y * 128;
    const int w    = tid >> 6;
    const int l    = tid & 63;
    const int wm   = w >> 1, wn = w & 1;
    const int lrow = l & 15;
    const int quad = l >> 4;

    f32x4 acc[4][4];
    #pragma unroll
    for (int i=0;i<4;i++)
        #pragma unroll
        for (int j=0;j<4;j++) acc[i][j] = (f32x4){0.f,0.f,0.f,0.f};

    for (int it = 0; it < 3; ++it){
        const int k0 = it * 64;
        if (it) __syncthreads();
        #pragma unroll
        for (int j = 0; j < 4; ++j){
            int e  = tid + j*256;
            int r  = e >> 3;
            int kk = (e & 7) << 3;
            int grow = row0 + r;
            uint4 va = make_uint4(0,0,0,0);
            if (grow < NM)
                va = *(const uint4*)(A + (size_t)grow*LDA_T + k0 + kk);
            *(uint4*)(&As[r][kk]) = va;
            uint4 vw = *(const uint4*)(W + (size_t)(col0 + r)*LDA_T + k0 + kk);
            *(uint4*)(&Ws[r][kk]) = vw;
        }
        __syncthreads();
        #pragma unroll
        for (int ks = 0; ks < 2; ++ks){
            int koff = ks*32 + quad*8;
            bf16x8 a_[4], b_[4];
            #pragma unroll
            for (int mi=0;mi<4;mi++)
                a_[mi] = *(const bf16x8*)(&As[wm*64 + mi*16 + lrow][koff]);
            #pragma unroll
            for (int ni=0;ni<4;ni++)
                b_[ni] = *(const bf16x8*)(&Ws[wn*64 + ni*16 + lrow][koff]);
            #pragma unroll
            for (int mi=0;mi<4;mi++)
                #pragma unroll
                for (int ni=0;ni<4;ni++)
                    acc[mi][ni] = __builtin_amdgcn_mfma_f32_16x16x32_bf16(
                        a_[mi], b_[ni], acc[mi][ni], 0, 0, 0);
        }
    }
    #pragma unroll
    for (int ni=0;ni<4;ni++){
        int col = col0 + wn*64 + ni*16 + lrow;
        float bv = bias[col];
        #pragma unroll
        for (int mi=0;mi<4;mi++){
            int rbase = row0 + wm*64 + mi*16 + quad*4;
            #pragma unroll
            for (int reg=0;reg<4;reg++){
                int grow = rbase + reg;
                if (grow < NM)
                    C[(size_t)grow*LDH + col] = __float2bfloat16(acc[mi][ni][reg] + bv);
            }
        }
    }
}

// ================= small fp32 GEMM (embedding / head)
#define BM 64
#define BN 128
#define BK 32
template<int EPI, int SPIN>
__global__ __launch_bounds__(256)
void gemm_tn(const float* __restrict__ T, int ldt, int R,
             const float* __restrict__ W, int ldw, int K, int O,
             const float* __restrict__ bias,
             float* __restrict__ C, int ldc)
{
    __shared__ float Ts[BM][BK+1];
    __shared__ float Ws2[BN][BK+1];
    const int tid = threadIdx.x;
    const int row0 = blockIdx.x * BM;
    const int tx = tid % 16;
    const int ty = tid / 16;
    float acc[4][8];
    #pragma unroll
    for (int i=0;i<4;i++)
        #pragma unroll
        for (int j=0;j<8;j++) acc[i][j]=0.f;

    for (int k0 = 0; k0 < K; k0 += BK) {
        #pragma unroll
        for (int i=0;i<(BM*BK)/256;i++){
            int e = tid + i*256;
            int r = e / BK, k = e % BK;
            int gr = row0 + r, gk = k0 + k;
            float v = 0.f;
            if (gr < R && gk < K){
                v = T[(size_t)gr*ldt + gk];
                if (SPIN) v = softplusf_(v);
            }
            Ts[r][k] = v;
        }
        #pragma unroll
        for (int i=0;i<(BN*BK)/256;i++){
            int e = tid + i*256;
            int r = e / BK, k = e % BK;
            int gk = k0 + k;
            Ws2[r][k] = (r < O && gk < K) ? W[(size_t)r*ldw + gk] : 0.f;
        }
        __syncthreads();
        #pragma unroll
        for (int k=0;k<BK;k++){
            float a_[4], b_[8];
            #pragma unroll
            for (int i=0;i<4;i++) a_[i] = Ts[ty*4+i][k];
            #pragma unroll
            for (int j=0;j<8;j++) b_[j] = Ws2[tx + j*16][k];
            #pragma unroll
            for (int i=0;i<4;i++)
                #pragma unroll
                for (int j=0;j<8;j++)
                    acc[i][j] += a_[i]*b_[j];
        }
        __syncthreads();
    }
    #pragma unroll
    for (int i=0;i<4;i++){
        int gr = row0 + ty*4 + i;
        if (gr >= R) continue;
        #pragma unroll
        for (int j=0;j<8;j++){
            int gc = tx + j*16;
            if (gc >= O) continue;
            float v = acc[i][j] + (bias ? bias[gc] : 0.f);
            if (EPI==1) v = softplusf_(v);
            C[(size_t)gr*ldc + gc] = v;
        }
    }
}

// ================= pack weights (bf16) + bias (fp32).
__global__ void pack_all(const float* __restrict__ fcW, const float* __restrict__ eW,
                         const float* __restrict__ W3, const float* __restrict__ fcb,
                         const float* __restrict__ eb, const float* __restrict__ b3,
                         __hip_bfloat16* __restrict__ WALL, float* __restrict__ BIAS)
{
    int i = blockIdx.x*blockDim.x + threadIdx.x;
    const int nW = NCONV*512*LDA_T;
    if (i < nW){
        int l = i/(512*LDA_T), rem = i%(512*LDA_T);
        int c = rem/LDA_T, k = rem%LDA_T;
        float v = 0.f;
        if (c < O1){
            if (k < K1) v = fcW[((size_t)l*O1 + c)*K1 + k];
        } else if (c < O1+OE){
            if (k < K1) v = eW[((size_t)l*OE + (c-O1))*K1 + k];
        } else if (c >= 256 && c < 384){
            int o = c - 256;
            const float* W3l = W3 + (size_t)l*O1*K3;
            if (k < AF)                        v = 0.5f * W3l[(size_t)o*K3 + k];          // Wa/2
            else if (k < 2*AF)                 v = W3l[(size_t)o*K3 + k];                 // Wj
            else if (k < K1)                   v = W3l[(size_t)o*K3 + 192 + (k-128)];     // Wij
        } else if (c >= 384){
            int o = c - 384;
            const float* W3l = W3 + (size_t)l*O1*K3;
            if (k < AF)                        v = 0.5f * W3l[(size_t)o*K3 + k];          // Wa/2
            else if (k < 2*AF)                 v = W3l[(size_t)o*K3 + k + AF];            // Wl
            else if (k < K1)                   v = W3l[(size_t)o*K3 + 233 + (k-128)];     // Wil
        }
        WALL[i] = __float2bfloat16(v);
    } else if (i < nW + NCONV*512){
        int m = i - nW;
        int l = m/512, c = m%512;
        float v = 0.f;
        if (c < O1)         v = fcb[l*O1 + c];
        else if (c < O1+OE) v = eb[l*OE + (c-O1)];
        else if (c >= 256)  v = 0.5f * b3[l*O1 + ((c-256)&127)];
        BIAS[m] = v;
    }
}

// ================= tot (bf16): [x | xn | e | 0], lda=192; 8 bf16 per thread
__global__ void gather_b(__hip_bfloat16* __restrict__ TOT, const float* __restrict__ X,
                         const float* __restrict__ E, const int* __restrict__ idx)
{
    int i = blockIdx.x*blockDim.x + threadIdx.x;
    if (i >= NM*24) return;
    int grp = i % 24, r = i / 24;
    int n = r / MNBR;
    float v[8];
    if (grp < 16){
        const float* src = (grp < 8) ? (X + (size_t)n*AF + grp*8)
                                     : (X + (size_t)idx[r]*AF + (grp-8)*8);
        #pragma unroll
        for (int j=0;j<8;j++) v[j] = src[j];
    } else {
        int base = (grp-16)*8;
        #pragma unroll
        for (int j=0;j<8;j++){
            int k = base + j;
            v[j] = (k < BFEA) ? E[(size_t)r*BFEA + k] : 0.f;
        }
    }
    __hip_bfloat16 o[8];
    #pragma unroll
    for (int j=0;j<8;j++) o[j] = __float2bfloat16(v[j]);
    *(uint4*)(TOT + (size_t)r*LDA_T + grp*8) = *(const uint4*)o;
}

// ================= fused stats over bf16 REST: h/he column sums + closed-form BN3
__global__ __launch_bounds__(256)
void stats_all(const __hip_bfloat16* __restrict__ REST,
               float* __restrict__ S1A, float* __restrict__ S2A,
               float* __restrict__ S13, float* __restrict__ S23)
{
    const int tid = threadIdx.x;
    const int n0 = blockIdx.x * 4;
    const int r0 = n0 * MNBR;
    if (tid < O1+OE){
        float s1 = 0.f, s2 = 0.f;
        #pragma unroll 4
        for (int j = 0; j < 4*MNBR; ++j){
            float v = b2f(REST[(size_t)(r0+j)*LDH + tid]);
            s1 += v; s2 += v*v;
        }
        atomicAdd(&S1A[tid], s1);
        atomicAdd(&S2A[tid], s2);
    }
    if (tid < O1){
        float s1 = 0.f, s2 = 0.f;
        for (int a = 0; a < 4; ++a){
            int n = n0 + a;
            float sp=0.f, spp=0.f, sq=0.f, sqq=0.f;
            #pragma unroll
            for (int m=0;m<MNBR;m++){
                const __hip_bfloat16* row = REST + (size_t)(n*MNBR+m)*LDH;
                float p = b2f(row[256 + tid]);
                float q = b2f(row[384 + tid]);
                sp += p; spp += p*p; sq += q; sqq += q*q;
            }
            s1 += 12.f*(sp+sq);
            s2 += 12.f*(spp+sqq) + 2.f*sp*sq;
        }
        atomicAdd(&S13[tid], s1);
        atomicAdd(&S23[tid], s2);
    }
}

// ================= BN finalize for all channels -> packed SC table
// SC[0..209]=sA, SC[256..465]=tA, SC[512..639]=s3, SC[640..767]=t3
__global__ void bn_fin_all(const float* __restrict__ S1A, const float* __restrict__ S2A,
                           const float* __restrict__ S13, const float* __restrict__ S23,
                           const float* __restrict__ g1, const float* __restrict__ b1,
                           const float* __restrict__ ge, const float* __restrict__ be,
                           const float* __restrict__ g3, const float* __restrict__ b3b,
                           float* __restrict__ SC)
{
    int c = threadIdx.x;   // 256
    if (c < O1+OE){
        float mean = S1A[c]*(1.f/NM);
        float var  = fmaxf(S2A[c]*(1.f/NM) - mean*mean, 0.f);
        float gg = (c < O1) ? g1[c] : ge[c-O1];
        float bb = (c < O1) ? b1[c] : be[c-O1];
        float sc = gg * rsqrtf(var + EPS_BN);
        SC[c] = sc; SC[256+c] = bb - sc*mean;
    }
    if (c < O1){
        float mean = S13[c]*(1.f/((float)NM*MNBR));
        float var  = fmaxf(S23[c]*(1.f/((float)NM*MNBR)) - mean*mean, 0.f);
        float sc = g3[c] * rsqrtf(var + EPS_BN);
        SC[512+c] = sc; SC[640+c] = b3b[c] - sc*mean;
    }
}

// ================= consumer: block = atom, 128 threads (2 waves x 6 m's each).
__global__ __launch_bounds__(128)
void consumer_k(const __hip_bfloat16* __restrict__ REST, const float* __restrict__ SC,
                float* __restrict__ TB, float* __restrict__ E)
{
    __shared__ float red[128];
    const int n = blockIdx.x;
    const int t = threadIdx.x;
    const int a = t & 63;
    const int g = t >> 6;     // 0..1
    const __hip_bfloat16* base = REST + (size_t)n*MNBR*LDH;

    float sha = SC[a],      tha = SC[256+a];
    float shb = SC[64+a],   thb = SC[256+64+a];
    float s3lo = SC[512+a], s3hi = SC[512+64+a];
    float t3lo = SC[640+a], t3hi = SC[640+64+a];

    float Qa[MNBR], Qb[MNBR];
    #pragma unroll
    for (int m=0;m<MNBR;m++){
        const __hip_bfloat16* row = base + (size_t)m*LDH;
        Qa[m] = s3lo*b2f(row[384+a]);
        Qb[m] = s3hi*b2f(row[448+a]);
    }
    float acc = 0.f;
    #pragma unroll
    for (int j=0;j<6;j++){
        const __hip_bfloat16* row = base + (size_t)(g*6+j)*LDH;
        acc += sigmoidf_(sha*b2f(row[a])+tha) * softplusf_(shb*b2f(row[64+a])+thb);
        float ua = s3lo*b2f(row[256+a]) + t3lo;
        float ub = s3hi*b2f(row[320+a]) + t3hi;
        #pragma unroll
        for (int l2=0;l2<MNBR;l2++)
            acc += sigmoidf_(ua + Qa[l2]) * softplusf_(ub + Qb[l2]);
    }
    red[t] = acc;
    __syncthreads();
    if (g == 0)
        TB[(size_t)n*AF + a] = red[a] + red[64+a];
    // edge update: idx = m*41+b consecutive -> coalesced E access
    for (int idx = t; idx < MNBR*BFEA; idx += 128){
        int m = idx / BFEA, b = idx % BFEA;
        const __hip_bfloat16* row = base + (size_t)m*LDH;
        float u = SC[O1+b]*b2f(row[O1+b])   + SC[256+O1+b];
        float v = SC[169+b]*b2f(row[169+b]) + SC[256+169+b];
        E[(size_t)n*MNBR*BFEA + idx] += sigmoidf_(u) * softplusf_(v);
    }
}

// ================= per-column sum/sumsq for TB
__global__ __launch_bounds__(64)
void tb_stats_k(const float* __restrict__ TB,
                float* __restrict__ S1, float* __restrict__ S2)
{
    int t = threadIdx.x;
    float s1 = 0.f, s2 = 0.f;
    for (int r = blockIdx.x; r < N_ATOM; r += gridDim.x){
        float v = TB[(size_t)r*AF + t];
        s1 += v; s2 += v*v;
    }
    atomicAdd(&S1[t], s1);
    atomicAdd(&S2[t], s2);
}

// ================= x = softplus(x + bn2(TB)), inline finalize
__global__ void x_update_k(float* __restrict__ X, const float* __restrict__ TB,
                           const float* __restrict__ S12, const float* __restrict__ S22,
                           const float* __restrict__ g2, const float* __restrict__ b2,
                           int total)
{
    int i = blockIdx.x*blockDim.x + threadIdx.x;
    if (i >= total) return;
    int a = i & (AF-1);
    float mean = S12[a]*(1.f/N_ATOM);
    float var  = fmaxf(S22[a]*(1.f/N_ATOM) - mean*mean, 0.f);
    float sc = g2[a]*rsqrtf(var + EPS_BN);
    X[i] = softplusf_(X[i] + sc*TB[i] + (b2[a] - sc*mean));
}

// ================= pooled mean per crystal + final dot
__global__ __launch_bounds__(128)
void pool_out_k(const float* __restrict__ Z, const int* __restrict__ seg,
                const float* __restrict__ outW, const float* __restrict__ outb,
                float* __restrict__ out)
{
    __shared__ float red[128];
    const int c = blockIdx.x;
    const int h = threadIdx.x;
    int l0, l1;
    {
        int l=0, r=N_ATOM;
        while (l<r){ int m=(l+r)>>1; if (seg[m] < c) l=m+1; else r=m; }
        l0 = l;
        l=l0; r=N_ATOM;
        while (l<r){ int m=(l+r)>>1; if (seg[m] < c+1) l=m+1; else r=m; }
        l1 = l;
    }
    float s = 0.f;
    for (int n = l0; n < l1; ++n) s += Z[(size_t)n*HID + h];
    float cnt = fmaxf((float)(l1-l0), 1.f);
    red[h] = (s/cnt) * outW[h];
    __syncthreads();
    for (int off=64; off>0; off>>=1){
        if (h < off) red[h] += red[h+off];
        __syncthreads();
    }
    if (h == 0) out[c] = red[0] + outb[0];
}

extern "C" void kernel_launch(void* const* d_in, const int* in_sizes, int n_in,
                              void* d_out, int out_size, void* d_ws, size_t ws_size,
                              hipStream_t stream)
{
    const float* atom_fea = (const float*)d_in[0];
    const float* nbr_fea  = (const float*)d_in[1];
    const int*   nbr_idx  = (const int*)d_in[2];
    const int*   site_seg = (const int*)d_in[3];
    const float* emb_W = (const float*)d_in[4];
    const float* emb_b = (const float*)d_in[5];
    const float* fcW   = (const float*)d_in[6];
    const float* fcb   = (const float*)d_in[7];
    const float* bn1_g = (const float*)d_in[8];
    const float* bn1_b = (const float*)d_in[9];
    const float* bn2_g = (const float*)d_in[10];
    const float* bn2_b = (const float*)d_in[11];
    const float* eW    = (const float*)d_in[12];
    const float* eb    = (const float*)d_in[13];
    const float* bne_g = (const float*)d_in[14];
    const float* bne_b = (const float*)d_in[15];
    const float* W3    = (const float*)d_in[16];
    const float* b3    = (const float*)d_in[17];
    const float* bn3_g = (const float*)d_in[18];
    const float* bn3_b = (const float*)d_in[19];
    const float* fc1W  = (const float*)d_in[20];
    const float* fc1b  = (const float*)d_in[21];
    const float* outW  = (const float*)d_in[22];
    const float* outb  = (const float*)d_in[23];

    // workspace layout (float units); REST now bf16
    float* ws   = (float*)d_ws;
    float* X    = ws;                        // 128000
    float* E    = ws + 128000;               // 984000
    __hip_bfloat16* TOT = (__hip_bfloat16*)(ws + 1112000);    // 24000*192 bf16 = 1152000 fl
    __hip_bfloat16* REST = (__hip_bfloat16*)(ws + 2264000);   // 24000*512 bf16 = 6144000 fl
    float* TB   = ws + 8408000;              // 128000
    float* ST   = ws + 8536000;              // 3*2048
    float* SC   = ws + 8542144;              // 1024
    __hip_bfloat16* WALL = (__hip_bfloat16*)(ws + 8543168);   // 3*512*192 bf16 = 147456 fl
    float* BIAS = ws + 8690624;              // 1536
    float* Z    = ws + 8692160;              // 256000

    {
        int tot = NCONV*512*LDA_T + NCONV*512;
        pack_all<<<(tot+255)/256, 256, 0, stream>>>(fcW, eW, W3, fcb, eb, b3, WALL, BIAS);
    }
    hipMemsetAsync(ST, 0, NCONV*2048*sizeof(float), stream);
    gemm_tn<0,0><<<(N_ATOM+BM-1)/BM, 256, 0, stream>>>(atom_fea, OFEA, N_ATOM,
                                                       emb_W, OFEA, OFEA, AF, emb_b, X, AF);
    hipMemcpyAsync(E, nbr_fea, (size_t)NM*BFEA*sizeof(float),
                   hipMemcpyDeviceToDevice, stream);

    for (int i = 0; i < NCONV; i++){
        const float* g1 = bn1_g + i*O1, *b1 = bn1_b + i*O1;
        const float* g2 = bn2_g + i*AF, *b2 = bn2_b + i*AF;
        const float* ge = bne_g + i*OE, *be = bne_b + i*OE;
        const float* g3 = bn3_g + i*O1, *b3b = bn3_b + i*O1;
        float* STL = ST + i*2048;
        float *S1A=STL, *S2A=STL+256, *S13=STL+512, *S23=STL+640, *S12=STL+768, *S22=STL+832;

        gather_b<<<(NM*24+255)/256, 256, 0, stream>>>(TOT, X, E, nbr_idx);
        {
            dim3 g((NM+127)/128, 4);
            gemm_bf16<<<g, 256, 0, stream>>>(TOT, WALL + (size_t)i*512*LDA_T,
                                             BIAS + i*512, REST);
        }
        stats_all<<<N_ATOM/4, 256, 0, stream>>>(REST, S1A, S2A, S13, S23);
        bn_fin_all<<<1, 256, 0, stream>>>(S1A, S2A, S13, S23,
                                          g1, b1, ge, be, g3, b3b, SC);
        consumer_k<<<N_ATOM, 128, 0, stream>>>(REST, SC, TB, E);
        tb_stats_k<<<128, 64, 0, stream>>>(TB, S12, S22);
        x_update_k<<<(N_ATOM*AF+255)/256, 256, 0, stream>>>(X, TB, S12, S22, g2, b2,
                                                            N_ATOM*AF);
    }

    // head: Z = softplus(softplus(X) @ fc1W^T + fc1b); pooled mean; out
    gemm_tn<1,1><<<(N_ATOM+BM-1)/BM, 256, 0, stream>>>(X, AF, N_ATOM, fc1W, AF, AF, HID,
                                                       fc1b, Z, HID);
    pool_out_k<<<NCRY, 128, 0, stream>>>(Z, site_seg, outW, outb, (float*)d_out);
}